// Round 15
// baseline (36.655 us; speedup 1.0000x reference)
//
#include <hip/hip_runtime.h>

// B=64, D=256, M=100
//   k(b,i,j) = sum_m s_i s_j min(|f_i|,|f_j|) * exp(T)      [0.5 absorbed]
//            = sum_m sign(f_j) * clamp(f_i, -|f_j|, |f_j|) * exp(T)
//   out = k - rowmean_i - rowmean_j (symmetric), triu-packed per batch.
// Two kernels (cross-block sync = 30-130us; rounds 7/8/10).
// Pass1: 640 blocks x 512 thr, full-M 64x64 tile, clamp+fdot2 loop; writes
//   SCALED UNCENTERED values straight to final triu slots (no tiles array)
//   + raw row/col partials to part.
// Pass2: pure streaming RMW: gather 96 row sums, out -= scale/D*(r_i+c_j).

#define NB 64
#define DD 256
#define MM 100
#define TILE 64
#define NUT 10                 // upper 64x64 tile-pairs of the 4x4 tile grid
#define TRI_PER_B 32896        // D*(D+1)/2
#define NTILE 640              // NB * NUT
#define NMQ 25                 // m-quads (4 m = 2 m2-slices each)

typedef unsigned int u32;
typedef _Float16 f16x2 __attribute__((ext_vector_type(2)));

__device__ __forceinline__ void tile_coords(int t, int& ti, int& tj) {
    int a = (t >= 4) + (t >= 7) + (t >= 9);
    int s = (a * (9 - a)) >> 1;   // 0,4,7,9
    ti = a;
    tj = t - s + a;
}

// For row-group g, the 4 (ut, side) slots covering its row sums.
// byte = ut | (side<<5): g0:{0A,1A,2A,3A} g1:{4A,5A,6A,1B} g2:{7A,8A,2B,5B} g3:{9A,3B,6B,8B}
__device__ __forceinline__ u32 slot_enc(int g) {
    return g == 0 ? 0x03020100u : g == 1 ? 0x21060504u
         : g == 2 ? 0x25220807u : 0x28262309u;
}

// XCD-local tile mapping: XCD x gets 80 consecutive tiles = 8 whole batches.
__device__ __forceinline__ int swz_bt(int w) { return (w & 7) * 80 + (w >> 3); }

extern "C" __global__ void __launch_bounds__(512, 5)
k_partial(const float* __restrict__ f, const float* __restrict__ temp,
          float* __restrict__ part, float* __restrict__ out) {
    __shared__ u32 As[2 * NMQ][TILE];    // 12.8 KB  [m2][row]
    __shared__ u32 Bs[NMQ][TILE][2];     // 12.8 KB  [mq][col][m2-slice]
    const int t = threadIdx.x;
    const int bt = swz_bt(blockIdx.x);   // 0..639
    const int b = bt / NUT;
    const int ut = bt % NUT;
    int ti, tj;
    tile_coords(ut, ti, tj);
    const int i0 = ti * TILE, j0 = tj * TILE;
    const float* fb = f + (size_t)b * DD * MM;

    // ---- stage full M as packed fp16 ----
    for (int l = t; l < TILE * NMQ; l += 512) {   // 1600 float4 per matrix
        const int il = l & 63;
        const int mq = l >> 6;                    // 0..24
        float4 v = *reinterpret_cast<const float4*>(fb + (size_t)(i0 + il) * MM + mq * 4);
        As[2 * mq + 0][il] = __builtin_bit_cast(u32, __builtin_amdgcn_cvt_pkrtz(v.x, v.y));
        As[2 * mq + 1][il] = __builtin_bit_cast(u32, __builtin_amdgcn_cvt_pkrtz(v.z, v.w));
        float4 w = *reinterpret_cast<const float4*>(fb + (size_t)(j0 + il) * MM + mq * 4);
        uint2 p;
        p.x = __builtin_bit_cast(u32, __builtin_amdgcn_cvt_pkrtz(w.x, w.y));
        p.y = __builtin_bit_cast(u32, __builtin_amdgcn_cvt_pkrtz(w.z, w.w));
        *reinterpret_cast<uint2*>(&Bs[mq][il][0]) = p;   // ds_write_b64
    }
    __syncthreads();

    // 4x2 micro-tile: rows rg*4..+3 (rg=t>>5), cols cg*2..+1 (cg=t&31)
    const int rg = t >> 5, cg = t & 31;
    float acc[4][2] = {};

    #pragma unroll 5
    for (int mq = 0; mq < NMQ; ++mq) {
        uint4 a0 = *reinterpret_cast<const uint4*>(&As[2 * mq + 0][rg * 4]); // b128
        uint4 a1 = *reinterpret_cast<const uint4*>(&As[2 * mq + 1][rg * 4]); // b128
        uint4 bb = *reinterpret_cast<const uint4*>(&Bs[mq][cg * 2][0]);      // b128
        const u32 bcol[2][2] = {{bb.x, bb.y}, {bb.z, bb.w}};
        #pragma unroll
        for (int c = 0; c < 2; ++c) {
            #pragma unroll
            for (int e = 0; e < 2; ++e) {         // m2-slice
                const u32 bw  = bcol[c][e];
                const u32 babu = bw & 0x7fff7fffu;                  // |b|
                const u32 bsou = (bw & 0x80008000u) | 0x3c003c00u;  // +-1 w/ b sign
                const f16x2 bab = __builtin_bit_cast(f16x2, babu);
                const f16x2 bso = __builtin_bit_cast(f16x2, bsou);
                const uint4& aa = e ? a1 : a0;
                const u32 av[4] = {aa.x, aa.y, aa.z, aa.w};
                #pragma unroll
                for (int q = 0; q < 4; ++q) {
                    f16x2 a = __builtin_bit_cast(f16x2, av[q]);
                    f16x2 lo = __builtin_elementwise_max(a, -bab);  // neg modifier
                    f16x2 cl = __builtin_elementwise_min(lo, bab);  // clamp
                    acc[q][c] = __builtin_amdgcn_fdot2(cl, bso, acc[q][c], false);
                }
            }
        }
    }

    // ---- scaled, UNCENTERED values straight to final triu slots ----
    const float scale = expf(temp[0]);   // 0.5 absorbed by sign-min identity
    float* ob = out + (size_t)b * TRI_PER_B;
    #pragma unroll
    for (int q = 0; q < 4; ++q) {
        const int i = i0 + rg * 4 + q;
        const int j0e = j0 + cg * 2;
        const float v0 = scale * acc[q][0];
        const float v1 = scale * acc[q][1];
        if (ti != tj) {      // cg-lanes contiguous -> coalesced float2 stores
            const int off = (i * (2 * DD - i + 1)) / 2 + (j0e - i);
            *reinterpret_cast<float2*>(ob + off) = make_float2(v0, v1);
        } else {
            if (j0e >= i)     ob[(i * (2 * DD - i + 1)) / 2 + (j0e - i)]     = v0;
            if (j0e + 1 >= i) ob[(i * (2 * DD - i + 1)) / 2 + (j0e + 1 - i)] = v1;
        }
    }

    // row partials (4 rows) / col partials (2 cols), raw (unscaled)
    float ra[4], cb[2];
    #pragma unroll
    for (int q = 0; q < 4; ++q) ra[q] = acc[q][0] + acc[q][1];
    #pragma unroll
    for (int c = 0; c < 2; ++c)
        cb[c] = (acc[0][c] + acc[1][c]) + (acc[2][c] + acc[3][c]);

    __syncthreads();                       // staging reads done; reuse As
    float* red  = reinterpret_cast<float*>(&As[0][0]);   // [32 cg][64 rows] 8KB
    float* red2 = red + 2048;                            // [16 rg][64 cols] 4KB
    #pragma unroll
    for (int q = 0; q < 4; ++q) red[cg * 64 + rg * 4 + q] = ra[q];
    #pragma unroll
    for (int c = 0; c < 2; ++c) red2[rg * 64 + cg * 2 + c] = cb[c];
    __syncthreads();

    float* pb = part + (size_t)bt * 128;
    if (t < TILE) {                          // row sums
        float s = 0.f;
        #pragma unroll
        for (int w = 0; w < 32; ++w) s += red[w * 64 + t];
        pb[t] = s;
    } else if (t < 2 * TILE && ti != tj) {   // col sums (off-diag only)
        const int u = t - TILE;
        float s = 0.f;
        #pragma unroll
        for (int w = 0; w < 16; ++w) s += red2[w * 64 + u];
        pb[64 + u] = s;
    }
}

// Pass 2: streaming RMW centering. 1280 blocks (tile x col-half).
extern "C" __global__ void __launch_bounds__(256)
k_center(const float* __restrict__ part, const float* __restrict__ temp,
         float* __restrict__ out) {
    __shared__ float rows_sh[96];   // [0..63] tile rows, [64..95] this half's cols
    const int t = threadIdx.x;
    const int unit = (blockIdx.x & 7) * 160 + (blockIdx.x >> 3);  // 0..1279
    const int bt = unit >> 1;
    const int half = unit & 1;
    const int b = bt / NUT;
    const int ut = bt % NUT;
    int ti, tj;
    tile_coords(ut, ti, tj);
    const int i0 = ti * TILE, j0 = tj * TILE + half * 32;
    const int tix = t >> 4, tiy = t & 15;

    if (t < 96) {
        const int isrow = (t < 64);
        const int u = isrow ? t : (half * 32 + (t - 64));
        const int g = isrow ? ti : tj;
        const u32 enc = slot_enc(g);
        float sum = 0.f;
        #pragma unroll
        for (int s = 0; s < 4; ++s) {
            const u32 byte = (enc >> (8 * s)) & 0xffu;
            const int ut_s = byte & 0x1f;
            const int side = byte >> 5;
            sum += part[(size_t)(b * NUT + ut_s) * 128 + side * 64 + u];
        }
        rows_sh[t] = sum;
    }
    __syncthreads();

    const float csc = expf(temp[0]) * (1.0f / DD);   // scale/D
    float rloc[4], cloc[2];
    #pragma unroll
    for (int q = 0; q < 4; ++q) rloc[q] = rows_sh[tix * 4 + q];
    #pragma unroll
    for (int c = 0; c < 2; ++c) {
        const int lc = tiy * 2 + c;          // local col within this half
        cloc[c] = (ti == tj) ? rows_sh[half * 32 + lc] : rows_sh[64 + lc];
    }

    float* ob = out + (size_t)b * TRI_PER_B;
    #pragma unroll
    for (int q = 0; q < 4; ++q) {
        const int i = i0 + tix * 4 + q;
        const int j0e = j0 + tiy * 2;
        const float s0 = csc * (rloc[q] + cloc[0]);
        const float s1 = csc * (rloc[q] + cloc[1]);
        if (ti != tj) {
            const int off = (i * (2 * DD - i + 1)) / 2 + (j0e - i);
            float2 v = *reinterpret_cast<const float2*>(ob + off);
            v.x -= s0; v.y -= s1;
            *reinterpret_cast<float2*>(ob + off) = v;
        } else {
            if (j0e >= i) {
                const int off = (i * (2 * DD - i + 1)) / 2 + (j0e - i);
                ob[off] -= s0;
            }
            if (j0e + 1 >= i) {
                const int off = (i * (2 * DD - i + 1)) / 2 + (j0e + 1 - i);
                ob[off] -= s1;
            }
        }
    }
}

extern "C" void kernel_launch(void* const* d_in, const int* in_sizes, int n_in,
                              void* d_out, int out_size, void* d_ws, size_t ws_size,
                              hipStream_t stream) {
    const float* f    = (const float*)d_in[0];
    const float* temp = (const float*)d_in[1];
    float* out  = (float*)d_out;
    float* part = (float*)d_ws;                        // 640*128 f32 = 328 KB

    k_partial<<<NTILE, 512, 0, stream>>>(f, temp, part, out);
    k_center<<<2 * NTILE, 256, 0, stream>>>(part, temp, out);
}

// Round 16
// 34.664 us; speedup vs baseline: 1.0574x; 1.0574x over previous
//
#include <hip/hip_runtime.h>

// B=64, D=256, M=100
//   k(b,i,j) = sum_m s_i s_j min(|f_i|,|f_j|) * exp(T)      [0.5 absorbed]
//            = sum_m sign(f_j) * clamp(f_i, -|f_j|, |f_j|) * exp(T)
//   out = k - rowmean_i - rowmean_j (symmetric), triu-packed per batch.
// Two kernels (cross-block sync = 30-130us; rounds 7/8/10).
// Pass1: 640 blocks x 512 threads, full-M 64x64 tile. Inner loop uses the
// clamp identity: raw-A (zero row prep) + pk_max(neg-mod)/pk_min/fdot2.
// B staged [mq][col][2] so one b128 feeds two m2-slices. Pass2: center+pack.
// CHAMPION (round 14): 34.7 us. Rounds 15 (RMW centering) / 12 (stagger) /
// 13 (8-wave) / 11 (split-N) all within +-2 us -> converged.

#define NB 64
#define DD 256
#define MM 100
#define TILE 64
#define NUT 10                 // upper 64x64 tile-pairs of the 4x4 tile grid
#define TRI_PER_B 32896        // D*(D+1)/2
#define NTILE 640              // NB * NUT
#define NMQ 25                 // m-quads (4 m = 2 m2-slices each)
#define TILE_F (TILE * TILE)

typedef unsigned int u32;
typedef _Float16 f16x2 __attribute__((ext_vector_type(2)));

__device__ __forceinline__ void tile_coords(int t, int& ti, int& tj) {
    int a = (t >= 4) + (t >= 7) + (t >= 9);
    int s = (a * (9 - a)) >> 1;   // 0,4,7,9
    ti = a;
    tj = t - s + a;
}

// For row-group g, the 4 (ut, side) slots covering its row sums.
// byte = ut | (side<<5): g0:{0A,1A,2A,3A} g1:{4A,5A,6A,1B} g2:{7A,8A,2B,5B} g3:{9A,3B,6B,8B}
__device__ __forceinline__ u32 slot_enc(int g) {
    return g == 0 ? 0x03020100u : g == 1 ? 0x21060504u
         : g == 2 ? 0x25220807u : 0x28262309u;
}

// XCD-local tile mapping: XCD x gets 80 consecutive tiles = 8 whole batches.
__device__ __forceinline__ int swz_bt(int w) { return (w & 7) * 80 + (w >> 3); }

extern "C" __global__ void __launch_bounds__(512, 5)
k_partial(const float* __restrict__ f, float* __restrict__ part,
          _Float16* __restrict__ tiles) {
    __shared__ u32 As[2 * NMQ][TILE];    // 12.8 KB  [m2][row]
    __shared__ u32 Bs[NMQ][TILE][2];     // 12.8 KB  [mq][col][m2-slice]
    const int t = threadIdx.x;
    const int bt = swz_bt(blockIdx.x);   // 0..639
    const int b = bt / NUT;
    const int ut = bt % NUT;
    int ti, tj;
    tile_coords(ut, ti, tj);
    const int i0 = ti * TILE, j0 = tj * TILE;
    const float* fb = f + (size_t)b * DD * MM;

    // ---- stage full M as packed fp16 ----
    for (int l = t; l < TILE * NMQ; l += 512) {   // 1600 float4 per matrix
        const int il = l & 63;
        const int mq = l >> 6;                    // 0..24
        float4 v = *reinterpret_cast<const float4*>(fb + (size_t)(i0 + il) * MM + mq * 4);
        As[2 * mq + 0][il] = __builtin_bit_cast(u32, __builtin_amdgcn_cvt_pkrtz(v.x, v.y));
        As[2 * mq + 1][il] = __builtin_bit_cast(u32, __builtin_amdgcn_cvt_pkrtz(v.z, v.w));
        float4 w = *reinterpret_cast<const float4*>(fb + (size_t)(j0 + il) * MM + mq * 4);
        uint2 p;
        p.x = __builtin_bit_cast(u32, __builtin_amdgcn_cvt_pkrtz(w.x, w.y));
        p.y = __builtin_bit_cast(u32, __builtin_amdgcn_cvt_pkrtz(w.z, w.w));
        *reinterpret_cast<uint2*>(&Bs[mq][il][0]) = p;   // ds_write_b64
    }
    __syncthreads();

    // 4x2 micro-tile: rows rg*4..+3 (rg=t>>5), cols cg*2..+1 (cg=t&31)
    const int rg = t >> 5, cg = t & 31;
    float acc[4][2] = {};

    #pragma unroll 5
    for (int mq = 0; mq < NMQ; ++mq) {
        uint4 a0 = *reinterpret_cast<const uint4*>(&As[2 * mq + 0][rg * 4]); // b128
        uint4 a1 = *reinterpret_cast<const uint4*>(&As[2 * mq + 1][rg * 4]); // b128
        uint4 bb = *reinterpret_cast<const uint4*>(&Bs[mq][cg * 2][0]);      // b128
        // bb = {col0 m2e, col0 m2o, col1 m2e, col1 m2o}
        const u32 bcol[2][2] = {{bb.x, bb.y}, {bb.z, bb.w}};
        #pragma unroll
        for (int c = 0; c < 2; ++c) {
            #pragma unroll
            for (int e = 0; e < 2; ++e) {         // m2-slice
                const u32 bw  = bcol[c][e];
                const u32 babu = bw & 0x7fff7fffu;                  // |b|
                const u32 bsou = (bw & 0x80008000u) | 0x3c003c00u;  // +-1 w/ b sign
                const f16x2 bab = __builtin_bit_cast(f16x2, babu);
                const f16x2 bso = __builtin_bit_cast(f16x2, bsou);
                const uint4& aa = e ? a1 : a0;
                const u32 av[4] = {aa.x, aa.y, aa.z, aa.w};
                #pragma unroll
                for (int q = 0; q < 4; ++q) {
                    f16x2 a = __builtin_bit_cast(f16x2, av[q]);
                    f16x2 lo = __builtin_elementwise_max(a, -bab);  // neg modifier
                    f16x2 cl = __builtin_elementwise_min(lo, bab);  // clamp
                    acc[q][c] = __builtin_amdgcn_fdot2(cl, bso, acc[q][c], false);
                }
            }
        }
    }

    // tile -> ws as f16; cg-lanes contiguous -> coalesced
    _Float16* tp = tiles + (size_t)bt * TILE_F;
    #pragma unroll
    for (int q = 0; q < 4; ++q) {
        *reinterpret_cast<u32*>(tp + (rg * 4 + q) * TILE + cg * 2) =
            __builtin_bit_cast(u32, __builtin_amdgcn_cvt_pkrtz(acc[q][0], acc[q][1]));
    }

    // row partials (4 rows) / col partials (2 cols)
    float ra[4], cb[2];
    #pragma unroll
    for (int q = 0; q < 4; ++q) ra[q] = acc[q][0] + acc[q][1];
    #pragma unroll
    for (int c = 0; c < 2; ++c)
        cb[c] = (acc[0][c] + acc[1][c]) + (acc[2][c] + acc[3][c]);

    __syncthreads();                       // staging reads done; reuse As
    float* red  = reinterpret_cast<float*>(&As[0][0]);   // [32 cg][64 rows] 8KB
    float* red2 = red + 2048;                            // [16 rg][64 cols] 4KB
    #pragma unroll
    for (int q = 0; q < 4; ++q) red[cg * 64 + rg * 4 + q] = ra[q];
    #pragma unroll
    for (int c = 0; c < 2; ++c) red2[rg * 64 + cg * 2 + c] = cb[c];
    __syncthreads();

    float* pb = part + (size_t)bt * 128;
    if (t < TILE) {                          // row sums
        float s = 0.f;
        #pragma unroll
        for (int w = 0; w < 32; ++w) s += red[w * 64 + t];
        pb[t] = s;
    } else if (t < 2 * TILE && ti != tj) {   // col sums (off-diag only)
        const int u = t - TILE;
        float s = 0.f;
        #pragma unroll
        for (int w = 0; w < 16; ++w) s += red2[w * 64 + u];
        pb[64 + u] = s;
    }
}

// Pass 2: 1280 blocks (tile x col-half): row-sum gather, center, triu-pack.
extern "C" __global__ void __launch_bounds__(256)
k_finalize(const float* __restrict__ part, const float* __restrict__ temp,
           const _Float16* __restrict__ tiles, float* __restrict__ out) {
    __shared__ float rows_sh[96];   // [0..63] tile rows, [64..95] this half's cols
    const int t = threadIdx.x;
    const int unit = (blockIdx.x & 7) * 160 + (blockIdx.x >> 3);  // 0..1279
    const int bt = unit >> 1;
    const int half = unit & 1;
    const int b = bt / NUT;
    const int ut = bt % NUT;
    int ti, tj;
    tile_coords(ut, ti, tj);
    const int i0 = ti * TILE, j0 = tj * TILE + half * 32;
    const int tix = t >> 4, tiy = t & 15;

    if (t < 96) {
        const int isrow = (t < 64);
        const int u = isrow ? t : (half * 32 + (t - 64));
        const int g = isrow ? ti : tj;
        const u32 enc = slot_enc(g);
        float sum = 0.f;
        #pragma unroll
        for (int s = 0; s < 4; ++s) {
            const u32 byte = (enc >> (8 * s)) & 0xffu;
            const int ut_s = byte & 0x1f;
            const int side = byte >> 5;
            sum += part[(size_t)(b * NUT + ut_s) * 128 + side * 64 + u];
        }
        rows_sh[t] = sum;
    }

    const _Float16* tp = tiles + (size_t)bt * TILE_F;
    float vv[4][2];
    #pragma unroll
    for (int q = 0; q < 4; ++q) {
        u32 w = *reinterpret_cast<const u32*>(
            tp + (tix * 4 + q) * TILE + half * 32 + tiy * 2);
        f16x2 hv = __builtin_bit_cast(f16x2, w);
        vv[q][0] = (float)hv.x;
        vv[q][1] = (float)hv.y;
    }
    __syncthreads();

    const float scale = expf(temp[0]);   // 0.5 absorbed by sign-min identity
    const float inv_d = 1.0f / DD;
    float rloc[4], cloc[2];
    #pragma unroll
    for (int q = 0; q < 4; ++q) rloc[q] = rows_sh[tix * 4 + q];
    #pragma unroll
    for (int c = 0; c < 2; ++c) {
        const int lc = tiy * 2 + c;          // local col within this half
        cloc[c] = (ti == tj) ? rows_sh[half * 32 + lc] : rows_sh[64 + lc];
    }

    float* ob = out + (size_t)b * TRI_PER_B;
    #pragma unroll
    for (int q = 0; q < 4; ++q) {
        const int i = i0 + tix * 4 + q;
        const int j0e = j0 + tiy * 2;
        float v0 = scale * (vv[q][0] - (rloc[q] + cloc[0]) * inv_d);
        float v1 = scale * (vv[q][1] - (rloc[q] + cloc[1]) * inv_d);
        if (ti != tj) {
            const int off = (i * (2 * DD - i + 1)) / 2 + (j0e - i);
            *reinterpret_cast<float2*>(ob + off) = make_float2(v0, v1);
        } else {
            if (j0e >= i)     ob[(i * (2 * DD - i + 1)) / 2 + (j0e - i)]     = v0;
            if (j0e + 1 >= i) ob[(i * (2 * DD - i + 1)) / 2 + (j0e + 1 - i)] = v1;
        }
    }
}

extern "C" void kernel_launch(void* const* d_in, const int* in_sizes, int n_in,
                              void* d_out, int out_size, void* d_ws, size_t ws_size,
                              hipStream_t stream) {
    const float* f    = (const float*)d_in[0];
    const float* temp = (const float*)d_in[1];
    float* out  = (float*)d_out;
    float* part = (float*)d_ws;                        // 640*128 f32 = 328 KB
    _Float16* tiles = (_Float16*)(part + NTILE * 128); // 640*4096 f16 = 5.25 MB

    k_partial<<<NTILE, 512, 0, stream>>>(f, part, tiles);
    k_finalize<<<2 * NTILE, 256, 0, stream>>>(part, temp, tiles, out);
}